// Round 4
// baseline (260.665 us; speedup 1.0000x reference)
//
#include <hip/hip_runtime.h>

// PositionalEncoding: out = emb * sqrt(1024) + pe[:S] (broadcast over B),
// plus doc_emb = masked cumsum of (src_org == 49) along S per column.
// Outputs concatenated in d_out: out [4096*8*1024] then doc [4096*8].
//
// R4: doc-scan blocks FIRST (no serial tail), elementwise = 2 rows/block,
// PLAIN loads (keep L3 hits on freshly-restored emb) + NONTEMPORAL stores
// (don't allocate the 134MB out stream in L2/L3 — R2 vs R3 isolated this
// as a ~13% lever).

constexpr int S_LEN   = 4096;
constexpr int B_COLS  = 8;
constexpr int DIM     = 1024;
constexpr int SPLIT   = 49;
constexpr int THREADS = 256;
constexpr int ROWS    = 2;                      // rows per elementwise block
constexpr int EW_BLOCKS = S_LEN / ROWS;         // 2048

typedef float f32x4 __attribute__((ext_vector_type(4)));

__global__ __launch_bounds__(THREADS)
void pe_row2nt_kernel(const float* __restrict__ emb,
                      const int*   __restrict__ src,
                      const float* __restrict__ pe,
                      float* __restrict__ out,
                      float* __restrict__ doc)
{
    if (blockIdx.x >= B_COLS) {
        // ---------- elementwise: two sequence rows per block ----------
        const int t  = threadIdx.x;                 // float4 lane within dim
        const int s0 = (blockIdx.x - B_COLS) * ROWS;
        const float scale = 32.0f;                  // sqrt(1024)
        constexpr int RQ = DIM / 4;                 // 256 float4 per dim
        constexpr int ROWQ = B_COLS * RQ;           // 2048 float4 per row slab

        const f32x4* __restrict__ emb4 = reinterpret_cast<const f32x4*>(emb);
        const f32x4* __restrict__ pe4  = reinterpret_cast<const f32x4*>(pe);
        f32x4* __restrict__ out4       = reinterpret_cast<f32x4*>(out);

        // pe for both rows -> registers (8x reuse each)
        const f32x4 p0 = pe4[(size_t)s0 * RQ + t];
        const f32x4 p1 = pe4[(size_t)(s0 + 1) * RQ + t];

        const size_t base = (size_t)s0 * ROWQ + t;

        f32x4 e[ROWS * B_COLS];
        #pragma unroll
        for (int b = 0; b < B_COLS; ++b)
            e[b] = emb4[base + (size_t)b * RQ];
        #pragma unroll
        for (int b = 0; b < B_COLS; ++b)
            e[B_COLS + b] = emb4[base + ROWQ + (size_t)b * RQ];

        #pragma unroll
        for (int b = 0; b < B_COLS; ++b) {
            f32x4 o;
            o.x = fmaf(e[b].x, scale, p0.x);
            o.y = fmaf(e[b].y, scale, p0.y);
            o.z = fmaf(e[b].z, scale, p0.z);
            o.w = fmaf(e[b].w, scale, p0.w);
            __builtin_nontemporal_store(o, &out4[base + (size_t)b * RQ]);
        }
        #pragma unroll
        for (int b = 0; b < B_COLS; ++b) {
            f32x4 o;
            o.x = fmaf(e[B_COLS + b].x, scale, p1.x);
            o.y = fmaf(e[B_COLS + b].y, scale, p1.y);
            o.z = fmaf(e[B_COLS + b].z, scale, p1.z);
            o.w = fmaf(e[B_COLS + b].w, scale, p1.w);
            __builtin_nontemporal_store(o, &out4[base + ROWQ + (size_t)b * RQ]);
        }
    } else {
        // ---------- doc segment scan: one block per batch column ----------
        const int b = blockIdx.x;                   // 0..7, scheduled first
        const int t = threadIdx.x;
        constexpr int PER = S_LEN / THREADS;        // 16 positions/thread
        const int base = t * PER;

        int m[PER + 1];
        #pragma unroll
        for (int j = 0; j <= PER; ++j) {
            const int s = base + j;
            m[j] = (s < S_LEN && src[s * B_COLS + b] == SPLIT) ? 1 : 0;
        }

        int local = 0;
        #pragma unroll
        for (int j = 0; j < PER; ++j) local += m[j];

        // wave64 inclusive scan of per-thread sums
        int v = local;
        #pragma unroll
        for (int off = 1; off < 64; off <<= 1) {
            const int u = __shfl_up(v, off, 64);
            if ((t & 63) >= off) v += u;
        }

        __shared__ int wsum[THREADS / 64];
        if ((t & 63) == 63) wsum[t >> 6] = v;
        __syncthreads();

        int excl = v - local;                        // exclusive within wave
        for (int w = 0; w < (t >> 6); ++w) excl += wsum[w];

        int cum = excl;
        #pragma unroll
        for (int j = 0; j < PER; ++j) {
            cum += m[j];
            doc[(base + j) * B_COLS + b] = m[j + 1] ? 0.0f : (float)cum;
        }
    }
}

extern "C" void kernel_launch(void* const* d_in, const int* in_sizes, int n_in,
                              void* d_out, int out_size, void* d_ws, size_t ws_size,
                              hipStream_t stream) {
    const float* emb = (const float*)d_in[0];   // [4096, 8, 1024] f32
    const int*   src = (const int*)d_in[1];     // [4096, 8, 1]    i32
    const float* pe  = (const float*)d_in[2];   // [5000, 1, 1024] f32

    float* out = (float*)d_out;                                  // 33,554,432 f32
    float* doc = out + (size_t)S_LEN * B_COLS * DIM;             // + 32,768 f32

    pe_row2nt_kernel<<<EW_BLOCKS + B_COLS, THREADS, 0, stream>>>(emb, src, pe, out, doc);
}

// Round 5
// 236.292 us; speedup vs baseline: 1.1031x; 1.1031x over previous
//
#include <hip/hip_runtime.h>

// PositionalEncoding: out = emb * sqrt(1024) + pe[:S] (broadcast over B),
// plus doc_emb = masked cumsum of (src_org == 49) along S per column.
// Outputs concatenated in d_out: out [4096*8*1024] then doc [4096*8].
//
// R5 = reproduce R2's measured-best structure exactly, + doc blocks first.
//  - 1 sequence row per block (4096 EW blocks): e[8] = 32 VGPR, total ~48
//    => full 8 waves/SIMD occupancy AND all 8 loads genuinely in flight.
//    (2-row variants wanted 64 VGPR for e[16], compiler chose 32 -> chunked
//     load/store serialization; R3/R4 were 91/97us vs R2's 78us.)
//  - NT load + NT store: keep both 134MB streams out of the dirty L2/L3
//    (harness pre-dirties ~680MB via restore+poison right before launch).
//  - doc scan at blockIdx 0..7: runs concurrently, no serial tail.

constexpr int S_LEN   = 4096;
constexpr int B_COLS  = 8;
constexpr int DIM     = 1024;
constexpr int SPLIT   = 49;
constexpr int THREADS = 256;

typedef float f32x4 __attribute__((ext_vector_type(4)));

__global__ __launch_bounds__(THREADS)
void pe_r5_kernel(const float* __restrict__ emb,
                  const int*   __restrict__ src,
                  const float* __restrict__ pe,
                  float* __restrict__ out,
                  float* __restrict__ doc)
{
    if (blockIdx.x >= B_COLS) {
        // ---------- elementwise: one sequence row per block ----------
        const int s = blockIdx.x - B_COLS;
        const int t = threadIdx.x;                  // float4 lane within dim
        const float scale = 32.0f;                  // sqrt(1024)
        constexpr int RQ = DIM / 4;                 // 256 float4 per dim

        const f32x4* __restrict__ emb4 = reinterpret_cast<const f32x4*>(emb);
        const f32x4* __restrict__ pe4  = reinterpret_cast<const f32x4*>(pe);
        f32x4* __restrict__ out4       = reinterpret_cast<f32x4*>(out);

        const size_t base = (size_t)s * (B_COLS * RQ) + t;   // [s, b=0, d4=t]

        // 8 independent NT loads in flight (32 VGPRs, fits under 64 easily)
        f32x4 e[B_COLS];
        #pragma unroll
        for (int b = 0; b < B_COLS; ++b)
            e[b] = __builtin_nontemporal_load(&emb4[base + (size_t)b * RQ]);

        // pe row -> registers once (8x reuse); plain load (tiny, L3-friendly)
        const f32x4 p = pe4[(size_t)s * RQ + t];

        #pragma unroll
        for (int b = 0; b < B_COLS; ++b) {
            f32x4 o;
            o.x = fmaf(e[b].x, scale, p.x);
            o.y = fmaf(e[b].y, scale, p.y);
            o.z = fmaf(e[b].z, scale, p.z);
            o.w = fmaf(e[b].w, scale, p.w);
            __builtin_nontemporal_store(o, &out4[base + (size_t)b * RQ]);
        }
    } else {
        // ---------- doc segment scan: one block per batch column ----------
        const int b = blockIdx.x;                   // 0..7, scheduled first
        const int t = threadIdx.x;
        constexpr int PER = S_LEN / THREADS;        // 16 positions/thread
        const int base = t * PER;

        int m[PER + 1];
        #pragma unroll
        for (int j = 0; j <= PER; ++j) {
            const int s = base + j;
            m[j] = (s < S_LEN && src[s * B_COLS + b] == SPLIT) ? 1 : 0;
        }

        int local = 0;
        #pragma unroll
        for (int j = 0; j < PER; ++j) local += m[j];

        // wave64 inclusive scan of per-thread sums
        int v = local;
        #pragma unroll
        for (int off = 1; off < 64; off <<= 1) {
            const int u = __shfl_up(v, off, 64);
            if ((t & 63) >= off) v += u;
        }

        __shared__ int wsum[THREADS / 64];
        if ((t & 63) == 63) wsum[t >> 6] = v;
        __syncthreads();

        int excl = v - local;                        // exclusive within wave
        for (int w = 0; w < (t >> 6); ++w) excl += wsum[w];

        int cum = excl;
        #pragma unroll
        for (int j = 0; j < PER; ++j) {
            cum += m[j];
            doc[(base + j) * B_COLS + b] = m[j + 1] ? 0.0f : (float)cum;
        }
    }
}

extern "C" void kernel_launch(void* const* d_in, const int* in_sizes, int n_in,
                              void* d_out, int out_size, void* d_ws, size_t ws_size,
                              hipStream_t stream) {
    const float* emb = (const float*)d_in[0];   // [4096, 8, 1024] f32
    const int*   src = (const int*)d_in[1];     // [4096, 8, 1]    i32
    const float* pe  = (const float*)d_in[2];   // [5000, 1, 1024] f32

    float* out = (float*)d_out;                                  // 33,554,432 f32
    float* doc = out + (size_t)S_LEN * B_COLS * DIM;             // + 32,768 f32

    pe_r5_kernel<<<S_LEN + B_COLS, THREADS, 0, stream>>>(emb, src, pe, out, doc);
}